// Round 13
// baseline (201.263 us; speedup 1.0000x reference)
//
#include <hip/hip_runtime.h>

#define B_ 4
#define N_ 1024
#define E_ 512
#define H_ 8
#define D_ 64
#define BH_ 32

typedef __bf16 bf16;
typedef __bf16 bf16x8 __attribute__((ext_vector_type(8)));
typedef __bf16 bf16x4 __attribute__((ext_vector_type(4)));
typedef float f32x4 __attribute__((ext_vector_type(4)));

#define MFMA16 __builtin_amdgcn_mfma_f32_16x16x32_bf16

typedef const __attribute__((address_space(1))) void* gas_t;
typedef __attribute__((address_space(3))) void* las_t;

__device__ __forceinline__ void gload16(const void* g, void* l) {
    __builtin_amdgcn_global_load_lds((gas_t)g, (las_t)l, 16, 0, 0);
}

// ---------- prep: all fp32 -> bf16 hi/lo conversions in one launch ----------
__global__ __launch_bounds__(256) void prep_all(
    const float* __restrict__ X, const float* __restrict__ Wq,
    const float* __restrict__ Wk, const float* __restrict__ Wv,
    const float* __restrict__ Wo,
    bf16* __restrict__ Xh, bf16* __restrict__ Xl,
    bf16* __restrict__ Wqh, bf16* __restrict__ Wql,
    bf16* __restrict__ Wkh, bf16* __restrict__ Wkl,
    bf16* __restrict__ Wvh,
    bf16* __restrict__ Woh, bf16* __restrict__ Wol)
{
    const int NX = B_ * N_ * E_;
    const int NW = E_ * E_;
    int i = blockIdx.x * 256 + threadIdx.x;
    if (i < NX) {
        float x = X[i]; bf16 h = (bf16)x;
        Xh[i] = h; Xl[i] = (bf16)(x - (float)h);
        return;
    }
    i -= NX;
    int w = i >> 18, j = i & (NW - 1);
    if (w == 0) { float x = Wq[j]; bf16 h = (bf16)x; Wqh[j] = h; Wql[j] = (bf16)(x - (float)h); }
    else if (w == 1) { float x = Wk[j]; bf16 h = (bf16)x; Wkh[j] = h; Wkl[j] = (bf16)(x - (float)h); }
    else if (w == 2) { float x = Wv[j]; Wvh[j] = (bf16)x; }
    else if (w == 3) { float x = Wo[j]; bf16 h = (bf16)x; Woh[j] = h; Wol[j] = (bf16)(x - (float)h); }
}

// ---------- fused QKV projection with W-tile LDS staging ----------
__global__ __launch_bounds__(256) void qkv_gemm(
    const bf16* __restrict__ Xh, const bf16* __restrict__ Xl,
    const bf16* __restrict__ Wqh, const bf16* __restrict__ Wql, const float* __restrict__ bq,
    const bf16* __restrict__ Wkh, const bf16* __restrict__ Wkl, const float* __restrict__ bk,
    const bf16* __restrict__ Wvh, const float* __restrict__ bvv,
    bf16* __restrict__ Qh, bf16* __restrict__ Ql,
    bf16* __restrict__ Kh, bf16* __restrict__ Kl,
    bf16* __restrict__ Vt)
{
    __shared__ alignas(16) bf16 wlds[2][2][64 * 32];
    __shared__ alignas(16) bf16 tlds[64 * 72];
    const int z = blockIdx.z;
    const int e0 = blockIdx.x * 64;
    const int m0 = blockIdx.y * 64;
    const int tid = threadIdx.x;
    const int w = tid >> 6, l = tid & 63, lr = l & 15, lg = l >> 4;
    const int h = e0 >> 6;
    const bool three = (z != 2);

    const bf16* Wh = (z == 0) ? Wqh : ((z == 1) ? Wkh : Wvh);
    const bf16* Wl = (z == 0) ? Wql : ((z == 1) ? Wkl : Wqh /*unused*/);

    const int wrow = 16 * w + (l >> 2);
    const int wcol = 8 * ((l & 3) ^ ((l >> 3) & 3));
    const bf16* whsrc = Wh + (size_t)(e0 + wrow) * E_ + wcol;
    const bf16* wlsrc = Wl + (size_t)(e0 + wrow) * E_ + wcol;

#define WSTAGE(k0, bi) do {                                  \
        gload16(whsrc + (k0), &wlds[bi][0][w * 512]);        \
        if (three) gload16(wlsrc + (k0), &wlds[bi][1][w * 512]); \
    } while (0)

    WSTAGE(0, 0);

    f32x4 acc[4] = {};
    const bf16* xh = &Xh[(size_t)(m0 + w * 16 + lr) * E_];
    const bf16* xl = &Xl[(size_t)(m0 + w * 16 + lr) * E_];

    for (int it = 0; it < 16; ++it) {
        const int k0 = it * 32;
        const int bi = it & 1;
        if (it < 15) {
            WSTAGE(k0 + 32, bi ^ 1);
            __builtin_amdgcn_sched_barrier(0);
            if (three) asm volatile("s_waitcnt vmcnt(2)" ::: "memory");
            else       asm volatile("s_waitcnt vmcnt(1)" ::: "memory");
        } else {
            asm volatile("s_waitcnt vmcnt(0)" ::: "memory");
        }
        __builtin_amdgcn_sched_barrier(0);
        __builtin_amdgcn_s_barrier();

        bf16x8 ah = *(const bf16x8*)(xh + k0 + lg * 8);
        bf16x8 al = three ? *(const bf16x8*)(xl + k0 + lg * 8) : ah;

        const char* whb = (const char*)&wlds[bi][0][0];
        const char* wlb = (const char*)&wlds[bi][1][0];
        const int wsw = ((lr >> 1) & 3) << 4;
#pragma unroll
        for (int t = 0; t < 4; ++t) {
            int rb = (16 * t + lr) * 64;
            bf16x8 bh = *(const bf16x8*)(whb + rb + ((lg * 16) ^ wsw));
            acc[t] = MFMA16(ah, bh, acc[t], 0, 0, 0);
            if (three) {
                bf16x8 bl = *(const bf16x8*)(wlb + rb + ((lg * 16) ^ wsw));
                acc[t] = MFMA16(al, bh, acc[t], 0, 0, 0);
                acc[t] = MFMA16(ah, bl, acc[t], 0, 0, 0);
            }
        }
        __builtin_amdgcn_s_barrier();
    }
#undef WSTAGE

    if (z == 2) {
        const float* bias = bvv;
#pragma unroll
        for (int t = 0; t < 4; ++t) {
            float bv = bias[e0 + 16 * t + lr];
#pragma unroll
            for (int r = 0; r < 4; ++r)
                tlds[(16 * t + lr) * 72 + w * 16 + lg * 4 + r] = (bf16)(acc[t][r] + bv);
        }
        __syncthreads();
        int d = tid >> 2, c0 = (tid & 3) * 16;
        int b = m0 >> 10, n = (m0 & (N_ - 1)) + c0;
        bf16x8* dst = (bf16x8*)&Vt[((size_t)(b * H_ + h) * D_ + d) * N_ + n];
        const bf16x8* s = (const bf16x8*)&tlds[d * 72 + c0];
        dst[0] = s[0];
        dst[1] = s[1];
        return;
    }

    const float* bias = z ? bk : bq;
    bf16* Oh = z ? Kh : Qh;
    bf16* Ol = z ? Kl : Ql;
#pragma unroll
    for (int t = 0; t < 4; ++t) {
        float bv = bias[e0 + 16 * t + lr];
#pragma unroll
        for (int r = 0; r < 4; ++r) {
            int m = m0 + w * 16 + lg * 4 + r;
            int b = m >> 10, n = m & (N_ - 1);
            float v = acc[t][r] + bv;
            bf16 hi = (bf16)v;
            size_t idx = ((size_t)(b * H_ + h) * N_ + n) * D_ + 16 * t + lr;
            Oh[idx] = hi;
            Ol[idx] = (bf16)(v - (float)hi);
        }
    }
}

// ---------- fused attention: ONE-SHOT block staging, no in-loop waits.
// Block = (head, 16 q-rows, 256-col k-chunk). Prologue: 8 x 1KB full-row
// mask bursts/wave -> __syncthreads (drains DMA + fence). Loop (2 x 128
// cols): K/V direct from L2, masks from LDS, zero barriers. Wave k-slice
// partials merged in-block via LDS overlay, guarded by __syncthreads()
// (R12's raw s_barrier had no compiler fence / lgkm drain -> WAR race). ----------
__global__ __launch_bounds__(256, 3) void attn_kernel(
    const bf16* __restrict__ Qh_, const bf16* __restrict__ Ql_,
    const bf16* __restrict__ Kh_, const bf16* __restrict__ Kl_,
    const bf16* __restrict__ Vt_,
    const float* __restrict__ rn,
    const float* __restrict__ addm, const float* __restrict__ multm,
    float* __restrict__ Opart, float* __restrict__ Mb, float* __restrict__ Lb)
{
    __shared__ alignas(16) float alds[16 * 256];   // 16 KB add-mask; later acc-merge scratch
    __shared__ alignas(16) float mlds[16 * 256];   // 16 KB mult-mask; later m/l scratch
    __shared__ alignas(16) bf16 plds[4][16 * 40];  // 5 KB -> 37.9 KB total

    // XCD-bijective swizzle: 8192 wg; each XCD gets 4 contiguous heads.
    const int flat = blockIdx.x;
    const int wg = (flat & 7) * 1024 + (flat >> 3);
    const int bh = wg >> 8;            // head [0,32)
    const int qg = (wg >> 2) & 63;     // q-group
    const int ck = wg & 3;             // k-chunk [0,4)
    const int q0 = qg * 16;
    const int kb = ck * 256;
    const int b = bh >> 3;
    const int tid = threadIdx.x;
    const int w = tid >> 6, l = tid & 63, lr = l & 15, lg = l >> 4;
    bf16* pw = &plds[w][0];

    // ---- one-shot mask stage: wave w stages rows 4w..4w+3, 1KB/row/mask ----
    const size_t mb0 = (size_t)bh * N_ * N_;
    {
#pragma unroll
        for (int j = 0; j < 4; ++j) {
            const int r_ = 4 * w + j;
            const int sw = (l * 16) ^ ((r_ & 7) << 4);   // XOR within the row's 1KB window
            const char* arow = (const char*)(addm + mb0 + (size_t)(q0 + r_) * N_ + kb);
            const char* mrow = (const char*)(multm + mb0 + (size_t)(q0 + r_) * N_ + kb);
            gload16(arow + sw, &alds[r_ * 256]);
            gload16(mrow + sw, &mlds[r_ * 256]);
        }
    }

    // ---- Q fragments + rn while masks stream ----
    const bf16* qb = &Qh_[((size_t)bh * N_ + q0 + lr) * D_];
    const bf16* qlb = &Ql_[((size_t)bh * N_ + q0 + lr) * D_];
    bf16x8 qh0 = *(const bf16x8*)(qb + lg * 8);
    bf16x8 qh1 = *(const bf16x8*)(qb + 32 + lg * 8);
    bf16x8 ql0 = *(const bf16x8*)(qlb + lg * 8);
    bf16x8 ql1 = *(const bf16x8*)(qlb + 32 + lg * 8);
    const float rnq = rn[b * N_ + q0 + lr] * 0.125f;

    asm volatile("s_waitcnt vmcnt(0)" ::: "memory");   // own DMA drained
    __syncthreads();                                   // full fence + barrier: all rows visible

    float mrun = -3e38f, lrun = 0.f;
    f32x4 acc[4] = {};

#pragma unroll
    for (int s = 0; s < 2; ++s) {
        const int kw = kb + s * 128 + 32 * w;    // this wave's 32-col slice

        // K (8) + V (4) direct loads (L2-resident)
        bf16x8 kh[2][2], kl[2][2];
#pragma unroll
        for (int t = 0; t < 2; ++t) {
            const bf16* kp = Kh_ + ((size_t)bh * N_ + kw + 16 * t + lr) * D_ + 8 * lg;
            const bf16* k2 = Kl_ + ((size_t)bh * N_ + kw + 16 * t + lr) * D_ + 8 * lg;
            kh[t][0] = *(const bf16x8*)kp;
            kh[t][1] = *(const bf16x8*)(kp + 32);
            kl[t][0] = *(const bf16x8*)k2;
            kl[t][1] = *(const bf16x8*)(k2 + 32);
        }
        bf16x8 vv[4];
#pragma unroll
        for (int t = 0; t < 4; ++t)
            vv[t] = *(const bf16x8*)(Vt_ + ((size_t)bh * D_ + 16 * t + lr) * N_ + kw + 8 * lg);

        // ---- S^T = K Q^T (hi/lo split) ----
        f32x4 z[2];
#pragma unroll
        for (int t = 0; t < 2; ++t) {
            f32x4 zz = {};
            zz = MFMA16(kh[t][0], qh0, zz, 0, 0, 0);
            zz = MFMA16(kh[t][1], qh1, zz, 0, 0, 0);
            zz = MFMA16(kh[t][0], ql0, zz, 0, 0, 0);
            zz = MFMA16(kh[t][1], ql1, zz, 0, 0, 0);
            zz = MFMA16(kl[t][0], qh0, zz, 0, 0, 0);
            zz = MFMA16(kl[t][1], qh1, zz, 0, 0, 0);
            z[t] = zz;
        }

        // ---- masks from LDS (swizzled f32x4 reads; row = q = lr) ----
        f32x4 ma[2], mm[2];
#pragma unroll
        for (int t = 0; t < 2; ++t) {
            const int cdw = s * 128 + 32 * w + 16 * t + 4 * lg;    // within-row dword
            const int off = lr * 1024 + ((cdw * 4) ^ ((lr & 7) << 4));
            ma[t] = *(const f32x4*)((const char*)alds + off);
            mm[t] = *(const f32x4*)((const char*)mlds + off);
        }

        float sv[2][4];
#pragma unroll
        for (int t = 0; t < 2; ++t)
#pragma unroll
            for (int r = 0; r < 4; ++r)
                sv[t][r] = z[t][r] * rnq + ma[t][r];

        // ---- per-lane online softmax (q = lr; reduce over lg via xor16/32) ----
        float vmax = sv[0][0];
#pragma unroll
        for (int t = 0; t < 2; ++t)
#pragma unroll
            for (int r = 0; r < 4; ++r) vmax = fmaxf(vmax, sv[t][r]);
        vmax = fmaxf(vmax, __shfl_xor(vmax, 16));
        vmax = fmaxf(vmax, __shfl_xor(vmax, 32));
        float mn = fmaxf(mrun, vmax);
        float rs = __expf(mrun - mn);
        mrun = mn;
        lrun *= rs;
#pragma unroll
        for (int t = 0; t < 4; ++t) acc[t] *= rs;
        float pe[2][4];
        float rsum = 0.f;
#pragma unroll
        for (int t = 0; t < 2; ++t)
#pragma unroll
            for (int r = 0; r < 4; ++r) { pe[t][r] = __expf(sv[t][r] - mn); rsum += pe[t][r]; }
        rsum += __shfl_xor(rsum, 16);
        rsum += __shfl_xor(rsum, 32);
        lrun += rsum;

        // ---- P_eff -> wave-private plds[q=lr][k 0..31] ----
#pragma unroll
        for (int t = 0; t < 2; ++t) {
            bf16x4 pk;
#pragma unroll
            for (int r = 0; r < 4; ++r) pk[r] = (bf16)(pe[t][r] * mm[t][r]);
            *(bf16x4*)(pw + lr * 40 + 16 * t + 4 * lg) = pk;
        }

        // ---- PV ----
        bf16x8 pa = *(const bf16x8*)(pw + lr * 40 + 8 * lg);
#pragma unroll
        for (int t = 0; t < 4; ++t)
            acc[t] = MFMA16(vv[t], pa, acc[t], 0, 0, 0);
    }

    __syncthreads();   // ALL waves' mask reads drained before LDS overlay (WAR fence)

    // ---- in-block merge of the 4 wave k-slices (exact online-softmax merge) ----
    float* accL = alds;              // [4][16][64] f32 = 16 KB
    float* mlW = mlds;               // [4][16]
    float* llW = mlds + 64;          // [4][16]
#pragma unroll
    for (int t = 0; t < 4; ++t)
        *(f32x4*)&accL[(w * 16 + lr) * 64 + 16 * t + 4 * lg] = acc[t];
    if (lg == 0) { mlW[w * 16 + lr] = mrun; llW[w * 16 + lr] = lrun; }
    __syncthreads();   // overlay writes visible to all waves

    float M = fmaxf(fmaxf(mlW[lr], mlW[16 + lr]), fmaxf(mlW[32 + lr], mlW[48 + lr]));
    float L = 0.f;
    f32x4 o = {};
#pragma unroll
    for (int cc = 0; cc < 4; ++cc) {
        float wgt = __expf(mlW[cc * 16 + lr] - M);
        L += wgt * llW[cc * 16 + lr];
        f32x4 a = *(const f32x4*)&accL[(cc * 16 + lr) * 64 + 16 * w + 4 * lg];
        o += wgt * a;
    }
    const size_t cb = ((size_t)ck * BH_ + bh) * N_;
    *(f32x4*)&Opart[(cb + q0 + lr) * D_ + 16 * w + 4 * lg] = o;
    if (w == 0 && lg == 0) { Mb[cb + q0 + lr] = M; Lb[cb + q0 + lr] = L; }
}

// ---------- merge partials (4 k-chunks) -> normalized attention out ----------
__global__ __launch_bounds__(256) void merge_kernel(
    const float* __restrict__ Opart, const float* __restrict__ Mb,
    const float* __restrict__ Lb,
    bf16* __restrict__ AOh, bf16* __restrict__ AOl, int ks)
{
    int idx = blockIdx.x * 256 + threadIdx.x;
    int bh = idx >> 14;
    int rem = idx & 16383;
    int q = rem >> 4, d4 = rem & 15;

    float M = -3e38f;
    for (int c = 0; c < ks; ++c)
        M = fmaxf(M, Mb[((size_t)c * BH_ + bh) * N_ + q]);
    float L = 0.f;
    f32x4 o = {};
    for (int c = 0; c < ks; ++c) {
        size_t base = ((size_t)c * BH_ + bh) * N_ + q;
        float wgt = __expf(Mb[base] - M);
        L += wgt * Lb[base];
        f32x4 v = *(const f32x4*)&Opart[base * D_ + d4 * 4];
        o += wgt * v;
    }
    float inv = 1.f / L;
    int b = bh >> 3, h = bh & 7;
    size_t ob = ((size_t)b * N_ + q) * E_ + h * D_ + d4 * 4;
    bf16x4 hi, lo;
#pragma unroll
    for (int j = 0; j < 4; ++j) {
        float x = o[j] * inv;
        bf16 hh = (bf16)x;
        hi[j] = hh;
        lo[j] = (bf16)(x - (float)hh);
    }
    *(bf16x4*)&AOh[ob] = hi;
    *(bf16x4*)&AOl[ob] = lo;
}

// ---------- output projection with W-tile LDS staging, fp32 out + bias ----------
__global__ __launch_bounds__(256) void out_gemm(
    const bf16* __restrict__ Ah, const bf16* __restrict__ Al,
    const bf16* __restrict__ Wh, const bf16* __restrict__ Wl,
    const float* __restrict__ bias,
    float* __restrict__ out)
{
    __shared__ alignas(16) bf16 wlds[2][2][64 * 32];
    const int e0 = blockIdx.x * 64;
    const int m0 = blockIdx.y * 64;
    const int tid = threadIdx.x;
    const int w = tid >> 6, l = tid & 63, lr = l & 15, lg = l >> 4;

    const int wrow = 16 * w + (l >> 2);
    const int wcol = 8 * ((l & 3) ^ ((l >> 3) & 3));
    const bf16* whsrc = Wh + (size_t)(e0 + wrow) * E_ + wcol;
    const bf16* wlsrc = Wl + (size_t)(e0 + wrow) * E_ + wcol;

#define WSTAGE(k0, bi) do {                               \
        gload16(whsrc + (k0), &wlds[bi][0][w * 512]);     \
        gload16(wlsrc + (k0), &wlds[bi][1][w * 512]);     \
    } while (0)

    WSTAGE(0, 0);

    f32x4 acc[4] = {};
    const bf16* ah_p = &Ah[(size_t)(m0 + w * 16 + lr) * E_];
    const bf16* al_p = &Al[(size_t)(m0 + w * 16 + lr) * E_];

    for (int it = 0; it < 16; ++it) {
        const int k0 = it * 32;
        const int bi = it & 1;
        if (it < 15) {
            WSTAGE(k0 + 32, bi ^ 1);
            __builtin_amdgcn_sched_barrier(0);
            asm volatile("s_waitcnt vmcnt(2)" ::: "memory");
        } else {
            asm volatile("s_waitcnt vmcnt(0)" ::: "memory");
        }
        __builtin_amdgcn_sched_barrier(0);
        __builtin_amdgcn_s_barrier();

        bf16x8 ah = *(const bf16x8*)(ah_p + k0 + lg * 8);
        bf16x8 al = *(const bf16x8*)(al_p + k0 + lg * 8);
        const char* whb = (const char*)&wlds[bi][0][0];
        const char* wlb = (const char*)&wlds[bi][1][0];
        const int wsw = ((lr >> 1) & 3) << 4;
#pragma unroll
        for (int t = 0; t < 4; ++t) {
            int rb = (16 * t + lr) * 64;
            bf16x8 bh = *(const bf16x8*)(whb + rb + ((lg * 16) ^ wsw));
            bf16x8 bl = *(const bf16x8*)(wlb + rb + ((lg * 16) ^ wsw));
            acc[t] = MFMA16(ah, bh, acc[t], 0, 0, 0);
            acc[t] = MFMA16(al, bh, acc[t], 0, 0, 0);
            acc[t] = MFMA16(ah, bl, acc[t], 0, 0, 0);
        }
        __builtin_amdgcn_s_barrier();
    }
#undef WSTAGE

#pragma unroll
    for (int t = 0; t < 4; ++t) {
        float bv = bias[e0 + 16 * t + lr];
#pragma unroll
        for (int r = 0; r < 4; ++r) {
            int m = m0 + w * 16 + lg * 4 + r;
            out[(size_t)m * E_ + e0 + 16 * t + lr] = acc[t][r] + bv;
        }
    }
}

extern "C" void kernel_launch(void* const* d_in, const int* in_sizes, int n_in,
                              void* d_out, int out_size, void* d_ws, size_t ws_size,
                              hipStream_t stream) {
    const float* X = (const float*)d_in[0];
    const float* rn = (const float*)d_in[1];
    const float* addm = (const float*)d_in[2];
    const float* multm = (const float*)d_in[3];
    const float* Wq = (const float*)d_in[4];
    const float* bq = (const float*)d_in[5];
    const float* Wk = (const float*)d_in[6];
    const float* bk = (const float*)d_in[7];
    const float* Wv = (const float*)d_in[8];
    const float* bv = (const float*)d_in[9];
    const float* Wo = (const float*)d_in[10];
    const float* bo = (const float*)d_in[11];
    float* out = (float*)d_out;

    const size_t SZ_X = (size_t)B_ * N_ * E_;
    const size_t SZ_W = (size_t)E_ * E_;

    bf16* p = (bf16*)d_ws;
    bf16* Xh = p;  p += SZ_X;
    bf16* Xl = p;  p += SZ_X;
    bf16* Wqh = p; p += SZ_W;
    bf16* Wql = p; p += SZ_W;
    bf16* Wkh = p; p += SZ_W;
    bf16* Wkl = p; p += SZ_W;
    bf16* Wvh = p; p += SZ_W;
    bf16* Woh = p; p += SZ_W;
    bf16* Wol = p; p += SZ_W;
    bf16* Qh = p;  p += SZ_X;
    bf16* Ql = p;  p += SZ_X;
    bf16* Kh = p;  p += SZ_X;
    bf16* Kl = p;  p += SZ_X;
    bf16* Vt = p;  p += SZ_X;
    bf16* AOh = p; p += SZ_X;
    bf16* AOl = p; p += SZ_X;

    const int nchunk = 4;   // k-chunks (in-block wave merge removes wave chunks)
    float* Opart = (float*)p;
    float* Mb = Opart + (size_t)nchunk * BH_ * N_ * D_;
    float* Lb = Mb + (size_t)nchunk * BH_ * N_;

    const int NPREP = B_ * N_ * E_ + 4 * E_ * E_;
    prep_all<<<dim3(NPREP / 256), 256, 0, stream>>>(X, Wq, Wk, Wv, Wo,
        Xh, Xl, Wqh, Wql, Wkh, Wkl, Wvh, Woh, Wol);

    dim3 gq(E_ / 64, (B_ * N_) / 64, 3);
    qkv_gemm<<<gq, 256, 0, stream>>>(Xh, Xl, Wqh, Wql, bq, Wkh, Wkl, bk, Wvh, bv,
                                     Qh, Ql, Kh, Kl, Vt);

    // 32 heads x 64 q-groups x 4 k-chunks = 8192 one-shot blocks
    attn_kernel<<<dim3(BH_ * 64 * 4), 256, 0, stream>>>(
        Qh, Ql, Kh, Kl, Vt, rn, addm, multm, Opart, Mb, Lb);

    merge_kernel<<<dim3((BH_ * N_ * (D_ / 4)) / 256), 256, 0, stream>>>(
        Opart, Mb, Lb, AOh, AOl, nchunk);

    dim3 gg(E_ / 64, (B_ * N_) / 64);
    out_gemm<<<gg, 256, 0, stream>>>(AOh, AOl, Woh, Wol, bo, out);
}

// Round 14
// 185.287 us; speedup vs baseline: 1.0862x; 1.0862x over previous
//
#include <hip/hip_runtime.h>

#define B_ 4
#define N_ 1024
#define E_ 512
#define H_ 8
#define D_ 64
#define BH_ 32

typedef __bf16 bf16;
typedef __bf16 bf16x8 __attribute__((ext_vector_type(8)));
typedef __bf16 bf16x4 __attribute__((ext_vector_type(4)));
typedef float f32x4 __attribute__((ext_vector_type(4)));

#define MFMA16 __builtin_amdgcn_mfma_f32_16x16x32_bf16

typedef const __attribute__((address_space(1))) void* gas_t;
typedef __attribute__((address_space(3))) void* las_t;

__device__ __forceinline__ void gload16(const void* g, void* l) {
    __builtin_amdgcn_global_load_lds((gas_t)g, (las_t)l, 16, 0, 0);
}

// ---------- prep: all fp32 -> bf16 hi/lo conversions in one launch ----------
__global__ __launch_bounds__(256) void prep_all(
    const float* __restrict__ X, const float* __restrict__ Wq,
    const float* __restrict__ Wk, const float* __restrict__ Wv,
    const float* __restrict__ Wo,
    bf16* __restrict__ Xh, bf16* __restrict__ Xl,
    bf16* __restrict__ Wqh, bf16* __restrict__ Wql,
    bf16* __restrict__ Wkh, bf16* __restrict__ Wkl,
    bf16* __restrict__ Wvh,
    bf16* __restrict__ Woh, bf16* __restrict__ Wol)
{
    const int NX = B_ * N_ * E_;
    const int NW = E_ * E_;
    int i = blockIdx.x * 256 + threadIdx.x;
    if (i < NX) {
        float x = X[i]; bf16 h = (bf16)x;
        Xh[i] = h; Xl[i] = (bf16)(x - (float)h);
        return;
    }
    i -= NX;
    int w = i >> 18, j = i & (NW - 1);
    if (w == 0) { float x = Wq[j]; bf16 h = (bf16)x; Wqh[j] = h; Wql[j] = (bf16)(x - (float)h); }
    else if (w == 1) { float x = Wk[j]; bf16 h = (bf16)x; Wkh[j] = h; Wkl[j] = (bf16)(x - (float)h); }
    else if (w == 2) { float x = Wv[j]; Wvh[j] = (bf16)x; }
    else if (w == 3) { float x = Wo[j]; bf16 h = (bf16)x; Woh[j] = h; Wol[j] = (bf16)(x - (float)h); }
}

// ---------- fused QKV projection with W-tile LDS staging ----------
__global__ __launch_bounds__(256) void qkv_gemm(
    const bf16* __restrict__ Xh, const bf16* __restrict__ Xl,
    const bf16* __restrict__ Wqh, const bf16* __restrict__ Wql, const float* __restrict__ bq,
    const bf16* __restrict__ Wkh, const bf16* __restrict__ Wkl, const float* __restrict__ bk,
    const bf16* __restrict__ Wvh, const float* __restrict__ bvv,
    bf16* __restrict__ Qh, bf16* __restrict__ Ql,
    bf16* __restrict__ Kh, bf16* __restrict__ Kl,
    bf16* __restrict__ Vt)
{
    __shared__ alignas(16) bf16 wlds[2][2][64 * 32];
    __shared__ alignas(16) bf16 tlds[64 * 72];
    const int z = blockIdx.z;
    const int e0 = blockIdx.x * 64;
    const int m0 = blockIdx.y * 64;
    const int tid = threadIdx.x;
    const int w = tid >> 6, l = tid & 63, lr = l & 15, lg = l >> 4;
    const int h = e0 >> 6;
    const bool three = (z != 2);

    const bf16* Wh = (z == 0) ? Wqh : ((z == 1) ? Wkh : Wvh);
    const bf16* Wl = (z == 0) ? Wql : ((z == 1) ? Wkl : Wqh /*unused*/);

    const int wrow = 16 * w + (l >> 2);
    const int wcol = 8 * ((l & 3) ^ ((l >> 3) & 3));
    const bf16* whsrc = Wh + (size_t)(e0 + wrow) * E_ + wcol;
    const bf16* wlsrc = Wl + (size_t)(e0 + wrow) * E_ + wcol;

#define WSTAGE(k0, bi) do {                                  \
        gload16(whsrc + (k0), &wlds[bi][0][w * 512]);        \
        if (three) gload16(wlsrc + (k0), &wlds[bi][1][w * 512]); \
    } while (0)

    WSTAGE(0, 0);

    f32x4 acc[4] = {};
    const bf16* xh = &Xh[(size_t)(m0 + w * 16 + lr) * E_];
    const bf16* xl = &Xl[(size_t)(m0 + w * 16 + lr) * E_];

    for (int it = 0; it < 16; ++it) {
        const int k0 = it * 32;
        const int bi = it & 1;
        if (it < 15) {
            WSTAGE(k0 + 32, bi ^ 1);
            __builtin_amdgcn_sched_barrier(0);
            if (three) asm volatile("s_waitcnt vmcnt(2)" ::: "memory");
            else       asm volatile("s_waitcnt vmcnt(1)" ::: "memory");
        } else {
            asm volatile("s_waitcnt vmcnt(0)" ::: "memory");
        }
        __builtin_amdgcn_sched_barrier(0);
        __builtin_amdgcn_s_barrier();

        bf16x8 ah = *(const bf16x8*)(xh + k0 + lg * 8);
        bf16x8 al = three ? *(const bf16x8*)(xl + k0 + lg * 8) : ah;

        const char* whb = (const char*)&wlds[bi][0][0];
        const char* wlb = (const char*)&wlds[bi][1][0];
        const int wsw = ((lr >> 1) & 3) << 4;
#pragma unroll
        for (int t = 0; t < 4; ++t) {
            int rb = (16 * t + lr) * 64;
            bf16x8 bh = *(const bf16x8*)(whb + rb + ((lg * 16) ^ wsw));
            acc[t] = MFMA16(ah, bh, acc[t], 0, 0, 0);
            if (three) {
                bf16x8 bl = *(const bf16x8*)(wlb + rb + ((lg * 16) ^ wsw));
                acc[t] = MFMA16(al, bh, acc[t], 0, 0, 0);
                acc[t] = MFMA16(ah, bl, acc[t], 0, 0, 0);
            }
        }
        __builtin_amdgcn_s_barrier();
    }
#undef WSTAGE

    if (z == 2) {
        const float* bias = bvv;
#pragma unroll
        for (int t = 0; t < 4; ++t) {
            float bv = bias[e0 + 16 * t + lr];
#pragma unroll
            for (int r = 0; r < 4; ++r)
                tlds[(16 * t + lr) * 72 + w * 16 + lg * 4 + r] = (bf16)(acc[t][r] + bv);
        }
        __syncthreads();
        int d = tid >> 2, c0 = (tid & 3) * 16;
        int b = m0 >> 10, n = (m0 & (N_ - 1)) + c0;
        bf16x8* dst = (bf16x8*)&Vt[((size_t)(b * H_ + h) * D_ + d) * N_ + n];
        const bf16x8* s = (const bf16x8*)&tlds[d * 72 + c0];
        dst[0] = s[0];
        dst[1] = s[1];
        return;
    }

    const float* bias = z ? bk : bq;
    bf16* Oh = z ? Kh : Qh;
    bf16* Ol = z ? Kl : Ql;
#pragma unroll
    for (int t = 0; t < 4; ++t) {
        float bv = bias[e0 + 16 * t + lr];
#pragma unroll
        for (int r = 0; r < 4; ++r) {
            int m = m0 + w * 16 + lg * 4 + r;
            int b = m >> 10, n = m & (N_ - 1);
            float v = acc[t][r] + bv;
            bf16 hi = (bf16)v;
            size_t idx = ((size_t)(b * H_ + h) * N_ + n) * D_ + 16 * t + lr;
            Oh[idx] = hi;
            Ol[idx] = (bf16)(v - (float)hi);
        }
    }
}

// ---------- fused attention: PRODUCER-CONSUMER wave specialization ----------
// 512 thr: waves 0-3 CONSUME (MFMA+softmax, k-split 32 cols each), waves 4-7
// PRODUCE (pure mask gload_lds bursts — separate vmcnt counter, so consumer
// waits can never drain the mask prefetch). 8 phases x 128 cols, ping-pong
// mask bufs, ONE __syncthreads per phase. K/V direct from L2 in consumers.
__global__ __launch_bounds__(512, 4) void attn_kernel(
    const bf16* __restrict__ Qh_, const bf16* __restrict__ Ql_,
    const bf16* __restrict__ Kh_, const bf16* __restrict__ Kl_,
    const bf16* __restrict__ Vt_,
    const float* __restrict__ rn,
    const float* __restrict__ addm, const float* __restrict__ multm,
    float* __restrict__ Opart, float* __restrict__ Mb, float* __restrict__ Lb)
{
    __shared__ alignas(16) float alds[2][16 * 128];   // 16 KB add-mask ping-pong
    __shared__ alignas(16) float mlds[2][16 * 128];   // 16 KB mult-mask ping-pong
    __shared__ alignas(16) bf16 plds[4][16 * 40];     // 5 KB -> 37.3 KB total

    // XCD-bijective swizzle: 2048 wg = 8 XCDs x 256; 4 contiguous heads/XCD.
    const int flat = blockIdx.x;
    const int wg = (flat & 7) * 256 + (flat >> 3);
    const int bh = wg >> 6;            // head [0,32)
    const int q0 = (wg & 63) * 16;     // q-block
    const int b = bh >> 3;
    const int tid = threadIdx.x;
    const int w = tid >> 6;            // 0-3 consumer, 4-7 producer
    const int l = tid & 63, lr = l & 15, lg = l >> 4;
    const size_t mb0 = (size_t)bh * N_ * N_;

    // ---------------- producer state ----------------
    const int p = w - 4;               // producer id 0..3 (valid when w>=4)
    const int prow = 4 * (p < 0 ? 0 : p) + 2 * 0;  // base; rows staged: 4p..4p+3

    // ---------------- consumer state ----------------
    f32x4 acc[4] = {};
    float mrun = -3e38f, lrun = 0.f;
    bf16x8 qh0, qh1, ql0, ql1;
    float rnq = 0.f;
    bf16* pw = &plds[w & 3][0];

    if (w < 4) {
        const bf16* qb = &Qh_[((size_t)bh * N_ + q0 + lr) * D_];
        const bf16* qlb = &Ql_[((size_t)bh * N_ + q0 + lr) * D_];
        qh0 = *(const bf16x8*)(qb + lg * 8);
        qh1 = *(const bf16x8*)(qb + 32 + lg * 8);
        ql0 = *(const bf16x8*)(qlb + lg * 8);
        ql1 = *(const bf16x8*)(qlb + 32 + lg * 8);
        rnq = rn[b * N_ + q0 + lr] * 0.125f;
    } else {
        // prologue: stage phase-0 masks into buf 0
#pragma unroll
        for (int j = 0; j < 2; ++j) {
            const int rp = 4 * p + 2 * j;
            const int r_ = rp + (l >> 5);
            const int so = ((l & 31) * 16) ^ ((r_ & 7) << 4);
            gload16((const char*)(addm + mb0 + (size_t)(q0 + r_) * N_) + so,
                    &alds[0][rp * 128]);
            gload16((const char*)(multm + mb0 + (size_t)(q0 + r_) * N_) + so,
                    &mlds[0][rp * 128]);
        }
    }
    __syncthreads();   // drains producer DMA (vmcnt 0) + barrier: buf0 ready

    for (int t = 0; t < 8; ++t) {
        const int bi = t & 1;

        if (w >= 4) {
            // -------- PRODUCER: stage phase t+1 (separate vmcnt counter) --------
            if (t < 7) {
                const int kv = (t + 1) * 128;
#pragma unroll
                for (int j = 0; j < 2; ++j) {
                    const int rp = 4 * p + 2 * j;
                    const int r_ = rp + (l >> 5);
                    const int so = ((l & 31) * 16) ^ ((r_ & 7) << 4);
                    gload16((const char*)(addm + mb0 + (size_t)(q0 + r_) * N_ + kv) + so,
                            &alds[bi ^ 1][rp * 128]);
                    gload16((const char*)(multm + mb0 + (size_t)(q0 + r_) * N_ + kv) + so,
                            &mlds[bi ^ 1][rp * 128]);
                }
            }
        } else {
            // -------- CONSUMER: compute phase t from buf bi --------
            const int kw = t * 128 + 32 * w;   // this wave's 32-col slice

            bf16x8 kh[2][2], kl[2][2];
#pragma unroll
            for (int u = 0; u < 2; ++u) {
                const bf16* kp = Kh_ + ((size_t)bh * N_ + kw + 16 * u + lr) * D_ + 8 * lg;
                const bf16* k2 = Kl_ + ((size_t)bh * N_ + kw + 16 * u + lr) * D_ + 8 * lg;
                kh[u][0] = *(const bf16x8*)kp;
                kh[u][1] = *(const bf16x8*)(kp + 32);
                kl[u][0] = *(const bf16x8*)k2;
                kl[u][1] = *(const bf16x8*)(k2 + 32);
            }
            bf16x8 vv[4];
#pragma unroll
            for (int u = 0; u < 4; ++u)
                vv[u] = *(const bf16x8*)(Vt_ + ((size_t)bh * D_ + 16 * u + lr) * N_ + kw + 8 * lg);

            // S^T = K Q^T (hi/lo split)
            f32x4 z[2];
#pragma unroll
            for (int u = 0; u < 2; ++u) {
                f32x4 zz = {};
                zz = MFMA16(kh[u][0], qh0, zz, 0, 0, 0);
                zz = MFMA16(kh[u][1], qh1, zz, 0, 0, 0);
                zz = MFMA16(kh[u][0], ql0, zz, 0, 0, 0);
                zz = MFMA16(kh[u][1], ql1, zz, 0, 0, 0);
                zz = MFMA16(kl[u][0], qh0, zz, 0, 0, 0);
                zz = MFMA16(kl[u][1], qh1, zz, 0, 0, 0);
                z[u] = zz;
            }

            // masks from LDS (swizzled f32x4; row = q = lr)
            f32x4 ma[2], mm[2];
#pragma unroll
            for (int u = 0; u < 2; ++u) {
                const int cdw = 32 * w + 16 * u + 4 * lg;
                const int off = lr * 512 + ((cdw * 4) ^ ((lr & 7) << 4));
                ma[u] = *(const f32x4*)((const char*)&alds[bi][0] + off);
                mm[u] = *(const f32x4*)((const char*)&mlds[bi][0] + off);
            }

            float sv[2][4];
#pragma unroll
            for (int u = 0; u < 2; ++u)
#pragma unroll
                for (int r = 0; r < 4; ++r)
                    sv[u][r] = z[u][r] * rnq + ma[u][r];

            // per-lane online softmax (q = lr; reduce over lg via xor16/32)
            float vmax = sv[0][0];
#pragma unroll
            for (int u = 0; u < 2; ++u)
#pragma unroll
                for (int r = 0; r < 4; ++r) vmax = fmaxf(vmax, sv[u][r]);
            vmax = fmaxf(vmax, __shfl_xor(vmax, 16));
            vmax = fmaxf(vmax, __shfl_xor(vmax, 32));
            float mn = fmaxf(mrun, vmax);
            float rs = __expf(mrun - mn);
            mrun = mn;
            lrun *= rs;
#pragma unroll
            for (int u = 0; u < 4; ++u) acc[u] *= rs;
            float pe[2][4];
            float rsum = 0.f;
#pragma unroll
            for (int u = 0; u < 2; ++u)
#pragma unroll
                for (int r = 0; r < 4; ++r) { pe[u][r] = __expf(sv[u][r] - mn); rsum += pe[u][r]; }
            rsum += __shfl_xor(rsum, 16);
            rsum += __shfl_xor(rsum, 32);
            lrun += rsum;

            // P_eff -> wave-private plds
#pragma unroll
            for (int u = 0; u < 2; ++u) {
                bf16x4 pk;
#pragma unroll
                for (int r = 0; r < 4; ++r) pk[r] = (bf16)(pe[u][r] * mm[u][r]);
                *(bf16x4*)(pw + lr * 40 + 16 * u + 4 * lg) = pk;
            }

            // PV
            bf16x8 pa = *(const bf16x8*)(pw + lr * 40 + 8 * lg);
#pragma unroll
            for (int u = 0; u < 4; ++u)
                acc[u] = MFMA16(vv[u], pa, acc[u], 0, 0, 0);
        }

        __syncthreads();   // phase gate: drains each wave's own counters
    }

    // ---- consumer epilogue: per-wave k-chunk partials ----
    if (w < 4) {
        const size_t cb = ((size_t)w * BH_ + bh) * N_;
        float* ob = &Opart[(cb + q0 + lr) * D_];
#pragma unroll
        for (int u = 0; u < 4; ++u)
            *(f32x4*)(ob + 16 * u + 4 * lg) = acc[u];
        if (lg == 0) {
            Mb[cb + q0 + lr] = mrun;
            Lb[cb + q0 + lr] = lrun;
        }
    }
    (void)prow;
}

// ---------- merge partials (4 k-chunks) -> normalized attention out ----------
__global__ __launch_bounds__(256) void merge_kernel(
    const float* __restrict__ Opart, const float* __restrict__ Mb,
    const float* __restrict__ Lb,
    bf16* __restrict__ AOh, bf16* __restrict__ AOl, int ks)
{
    int idx = blockIdx.x * 256 + threadIdx.x;
    int bh = idx >> 14;
    int rem = idx & 16383;
    int q = rem >> 4, d4 = rem & 15;

    float M = -3e38f;
    for (int c = 0; c < ks; ++c)
        M = fmaxf(M, Mb[((size_t)c * BH_ + bh) * N_ + q]);
    float L = 0.f;
    f32x4 o = {};
    for (int c = 0; c < ks; ++c) {
        size_t base = ((size_t)c * BH_ + bh) * N_ + q;
        float wgt = __expf(Mb[base] - M);
        L += wgt * Lb[base];
        f32x4 v = *(const f32x4*)&Opart[base * D_ + d4 * 4];
        o += wgt * v;
    }
    float inv = 1.f / L;
    int b = bh >> 3, h = bh & 7;
    size_t ob = ((size_t)b * N_ + q) * E_ + h * D_ + d4 * 4;
    bf16x4 hi, lo;
#pragma unroll
    for (int j = 0; j < 4; ++j) {
        float x = o[j] * inv;
        bf16 hh = (bf16)x;
        hi[j] = hh;
        lo[j] = (bf16)(x - (float)hh);
    }
    *(bf16x4*)&AOh[ob] = hi;
    *(bf16x4*)&AOl[ob] = lo;
}

// ---------- output projection with W-tile LDS staging, fp32 out + bias ----------
__global__ __launch_bounds__(256) void out_gemm(
    const bf16* __restrict__ Ah, const bf16* __restrict__ Al,
    const bf16* __restrict__ Wh, const bf16* __restrict__ Wl,
    const float* __restrict__ bias,
    float* __restrict__ out)
{
    __shared__ alignas(16) bf16 wlds[2][2][64 * 32];
    const int e0 = blockIdx.x * 64;
    const int m0 = blockIdx.y * 64;
    const int tid = threadIdx.x;
    const int w = tid >> 6, l = tid & 63, lr = l & 15, lg = l >> 4;

    const int wrow = 16 * w + (l >> 2);
    const int wcol = 8 * ((l & 3) ^ ((l >> 3) & 3));
    const bf16* whsrc = Wh + (size_t)(e0 + wrow) * E_ + wcol;
    const bf16* wlsrc = Wl + (size_t)(e0 + wrow) * E_ + wcol;

#define WSTAGE(k0, bi) do {                               \
        gload16(whsrc + (k0), &wlds[bi][0][w * 512]);     \
        gload16(wlsrc + (k0), &wlds[bi][1][w * 512]);     \
    } while (0)

    WSTAGE(0, 0);

    f32x4 acc[4] = {};
    const bf16* ah_p = &Ah[(size_t)(m0 + w * 16 + lr) * E_];
    const bf16* al_p = &Al[(size_t)(m0 + w * 16 + lr) * E_];

    for (int it = 0; it < 16; ++it) {
        const int k0 = it * 32;
        const int bi = it & 1;
        if (it < 15) {
            WSTAGE(k0 + 32, bi ^ 1);
            __builtin_amdgcn_sched_barrier(0);
            asm volatile("s_waitcnt vmcnt(2)" ::: "memory");
        } else {
            asm volatile("s_waitcnt vmcnt(0)" ::: "memory");
        }
        __builtin_amdgcn_sched_barrier(0);
        __builtin_amdgcn_s_barrier();

        bf16x8 ah = *(const bf16x8*)(ah_p + k0 + lg * 8);
        bf16x8 al = *(const bf16x8*)(al_p + k0 + lg * 8);
        const char* whb = (const char*)&wlds[bi][0][0];
        const char* wlb = (const char*)&wlds[bi][1][0];
        const int wsw = ((lr >> 1) & 3) << 4;
#pragma unroll
        for (int t = 0; t < 4; ++t) {
            int rb = (16 * t + lr) * 64;
            bf16x8 bh = *(const bf16x8*)(whb + rb + ((lg * 16) ^ wsw));
            bf16x8 bl = *(const bf16x8*)(wlb + rb + ((lg * 16) ^ wsw));
            acc[t] = MFMA16(ah, bh, acc[t], 0, 0, 0);
            acc[t] = MFMA16(al, bh, acc[t], 0, 0, 0);
            acc[t] = MFMA16(ah, bl, acc[t], 0, 0, 0);
        }
        __builtin_amdgcn_s_barrier();
    }
#undef WSTAGE

#pragma unroll
    for (int t = 0; t < 4; ++t) {
        float bv = bias[e0 + 16 * t + lr];
#pragma unroll
        for (int r = 0; r < 4; ++r) {
            int m = m0 + w * 16 + lg * 4 + r;
            out[(size_t)m * E_ + e0 + 16 * t + lr] = acc[t][r] + bv;
        }
    }
}

extern "C" void kernel_launch(void* const* d_in, const int* in_sizes, int n_in,
                              void* d_out, int out_size, void* d_ws, size_t ws_size,
                              hipStream_t stream) {
    const float* X = (const float*)d_in[0];
    const float* rn = (const float*)d_in[1];
    const float* addm = (const float*)d_in[2];
    const float* multm = (const float*)d_in[3];
    const float* Wq = (const float*)d_in[4];
    const float* bq = (const float*)d_in[5];
    const float* Wk = (const float*)d_in[6];
    const float* bk = (const float*)d_in[7];
    const float* Wv = (const float*)d_in[8];
    const float* bv = (const float*)d_in[9];
    const float* Wo = (const float*)d_in[10];
    const float* bo = (const float*)d_in[11];
    float* out = (float*)d_out;

    const size_t SZ_X = (size_t)B_ * N_ * E_;
    const size_t SZ_W = (size_t)E_ * E_;

    bf16* p = (bf16*)d_ws;
    bf16* Xh = p;  p += SZ_X;
    bf16* Xl = p;  p += SZ_X;
    bf16* Wqh = p; p += SZ_W;
    bf16* Wql = p; p += SZ_W;
    bf16* Wkh = p; p += SZ_W;
    bf16* Wkl = p; p += SZ_W;
    bf16* Wvh = p; p += SZ_W;
    bf16* Woh = p; p += SZ_W;
    bf16* Wol = p; p += SZ_W;
    bf16* Qh = p;  p += SZ_X;
    bf16* Ql = p;  p += SZ_X;
    bf16* Kh = p;  p += SZ_X;
    bf16* Kl = p;  p += SZ_X;
    bf16* Vt = p;  p += SZ_X;
    bf16* AOh = p; p += SZ_X;
    bf16* AOl = p; p += SZ_X;

    const int nchunk = 4;   // consumer-wave k-slices
    float* Opart = (float*)p;
    float* Mb = Opart + (size_t)nchunk * BH_ * N_ * D_;
    float* Lb = Mb + (size_t)nchunk * BH_ * N_;

    const int NPREP = B_ * N_ * E_ + 4 * E_ * E_;
    prep_all<<<dim3(NPREP / 256), 256, 0, stream>>>(X, Wq, Wk, Wv, Wo,
        Xh, Xl, Wqh, Wql, Wkh, Wkl, Wvh, Woh, Wol);

    dim3 gq(E_ / 64, (B_ * N_) / 64, 3);
    qkv_gemm<<<gq, 256, 0, stream>>>(Xh, Xl, Wqh, Wql, bq, Wkh, Wkl, bk, Wvh, bv,
                                     Qh, Ql, Kh, Kl, Vt);

    // 32 heads x 64 q-groups = 2048 blocks x 512 threads (4 producer + 4 consumer waves)
    attn_kernel<<<dim3(BH_ * 64), 512, 0, stream>>>(
        Qh, Ql, Kh, Kl, Vt, rn, addm, multm, Opart, Mb, Lb);

    merge_kernel<<<dim3((BH_ * N_ * (D_ / 4)) / 256), 256, 0, stream>>>(
        Opart, Mb, Lb, AOh, AOl, nchunk);

    dim3 gg(E_ / 64, (B_ * N_) / 64);
    out_gemm<<<gg, 256, 0, stream>>>(AOh, AOl, Woh, Wol, bo, out);
}

// Round 15
// 183.324 us; speedup vs baseline: 1.0979x; 1.0107x over previous
//
#include <hip/hip_runtime.h>

#define B_ 4
#define N_ 1024
#define E_ 512
#define H_ 8
#define D_ 64
#define BH_ 32

typedef __bf16 bf16;
typedef __bf16 bf16x8 __attribute__((ext_vector_type(8)));
typedef __bf16 bf16x4 __attribute__((ext_vector_type(4)));
typedef float f32x4 __attribute__((ext_vector_type(4)));

#define MFMA16 __builtin_amdgcn_mfma_f32_16x16x32_bf16

typedef const __attribute__((address_space(1))) void* gas_t;
typedef __attribute__((address_space(3))) void* las_t;

__device__ __forceinline__ void gload16(const void* g, void* l) {
    __builtin_amdgcn_global_load_lds((gas_t)g, (las_t)l, 16, 0, 0);
}

// ---------- prep: all fp32 -> bf16 hi/lo conversions in one launch ----------
__global__ __launch_bounds__(256) void prep_all(
    const float* __restrict__ X, const float* __restrict__ Wq,
    const float* __restrict__ Wk, const float* __restrict__ Wv,
    const float* __restrict__ Wo,
    bf16* __restrict__ Xh, bf16* __restrict__ Xl,
    bf16* __restrict__ Wqh, bf16* __restrict__ Wql,
    bf16* __restrict__ Wkh, bf16* __restrict__ Wkl,
    bf16* __restrict__ Wvh,
    bf16* __restrict__ Woh, bf16* __restrict__ Wol)
{
    const int NX = B_ * N_ * E_;
    const int NW = E_ * E_;
    int i = blockIdx.x * 256 + threadIdx.x;
    if (i < NX) {
        float x = X[i]; bf16 h = (bf16)x;
        Xh[i] = h; Xl[i] = (bf16)(x - (float)h);
        return;
    }
    i -= NX;
    int w = i >> 18, j = i & (NW - 1);
    if (w == 0) { float x = Wq[j]; bf16 h = (bf16)x; Wqh[j] = h; Wql[j] = (bf16)(x - (float)h); }
    else if (w == 1) { float x = Wk[j]; bf16 h = (bf16)x; Wkh[j] = h; Wkl[j] = (bf16)(x - (float)h); }
    else if (w == 2) { float x = Wv[j]; Wvh[j] = (bf16)x; }
    else if (w == 3) { float x = Wo[j]; bf16 h = (bf16)x; Woh[j] = h; Wol[j] = (bf16)(x - (float)h); }
}

// ---------- fused QKV projection with W-tile LDS staging ----------
__global__ __launch_bounds__(256) void qkv_gemm(
    const bf16* __restrict__ Xh, const bf16* __restrict__ Xl,
    const bf16* __restrict__ Wqh, const bf16* __restrict__ Wql, const float* __restrict__ bq,
    const bf16* __restrict__ Wkh, const bf16* __restrict__ Wkl, const float* __restrict__ bk,
    const bf16* __restrict__ Wvh, const float* __restrict__ bvv,
    bf16* __restrict__ Qh, bf16* __restrict__ Ql,
    bf16* __restrict__ Kh, bf16* __restrict__ Kl,
    bf16* __restrict__ Vt)
{
    __shared__ alignas(16) bf16 wlds[2][2][64 * 32];
    __shared__ alignas(16) bf16 tlds[64 * 72];
    const int z = blockIdx.z;
    const int e0 = blockIdx.x * 64;
    const int m0 = blockIdx.y * 64;
    const int tid = threadIdx.x;
    const int w = tid >> 6, l = tid & 63, lr = l & 15, lg = l >> 4;
    const int h = e0 >> 6;
    const bool three = (z != 2);

    const bf16* Wh = (z == 0) ? Wqh : ((z == 1) ? Wkh : Wvh);
    const bf16* Wl = (z == 0) ? Wql : ((z == 1) ? Wkl : Wqh /*unused*/);

    const int wrow = 16 * w + (l >> 2);
    const int wcol = 8 * ((l & 3) ^ ((l >> 3) & 3));
    const bf16* whsrc = Wh + (size_t)(e0 + wrow) * E_ + wcol;
    const bf16* wlsrc = Wl + (size_t)(e0 + wrow) * E_ + wcol;

#define WSTAGE(k0, bi) do {                                  \
        gload16(whsrc + (k0), &wlds[bi][0][w * 512]);        \
        if (three) gload16(wlsrc + (k0), &wlds[bi][1][w * 512]); \
    } while (0)

    WSTAGE(0, 0);

    f32x4 acc[4] = {};
    const bf16* xh = &Xh[(size_t)(m0 + w * 16 + lr) * E_];
    const bf16* xl = &Xl[(size_t)(m0 + w * 16 + lr) * E_];

    for (int it = 0; it < 16; ++it) {
        const int k0 = it * 32;
        const int bi = it & 1;
        if (it < 15) {
            WSTAGE(k0 + 32, bi ^ 1);
            __builtin_amdgcn_sched_barrier(0);
            if (three) asm volatile("s_waitcnt vmcnt(2)" ::: "memory");
            else       asm volatile("s_waitcnt vmcnt(1)" ::: "memory");
        } else {
            asm volatile("s_waitcnt vmcnt(0)" ::: "memory");
        }
        __builtin_amdgcn_sched_barrier(0);
        __builtin_amdgcn_s_barrier();

        bf16x8 ah = *(const bf16x8*)(xh + k0 + lg * 8);
        bf16x8 al = three ? *(const bf16x8*)(xl + k0 + lg * 8) : ah;

        const char* whb = (const char*)&wlds[bi][0][0];
        const char* wlb = (const char*)&wlds[bi][1][0];
        const int wsw = ((lr >> 1) & 3) << 4;
#pragma unroll
        for (int t = 0; t < 4; ++t) {
            int rb = (16 * t + lr) * 64;
            bf16x8 bh = *(const bf16x8*)(whb + rb + ((lg * 16) ^ wsw));
            acc[t] = MFMA16(ah, bh, acc[t], 0, 0, 0);
            if (three) {
                bf16x8 bl = *(const bf16x8*)(wlb + rb + ((lg * 16) ^ wsw));
                acc[t] = MFMA16(al, bh, acc[t], 0, 0, 0);
                acc[t] = MFMA16(ah, bl, acc[t], 0, 0, 0);
            }
        }
        __builtin_amdgcn_s_barrier();
    }
#undef WSTAGE

    if (z == 2) {
        const float* bias = bvv;
#pragma unroll
        for (int t = 0; t < 4; ++t) {
            float bv = bias[e0 + 16 * t + lr];
#pragma unroll
            for (int r = 0; r < 4; ++r)
                tlds[(16 * t + lr) * 72 + w * 16 + lg * 4 + r] = (bf16)(acc[t][r] + bv);
        }
        __syncthreads();
        int d = tid >> 2, c0 = (tid & 3) * 16;
        int b = m0 >> 10, n = (m0 & (N_ - 1)) + c0;
        bf16x8* dst = (bf16x8*)&Vt[((size_t)(b * H_ + h) * D_ + d) * N_ + n];
        const bf16x8* s = (const bf16x8*)&tlds[d * 72 + c0];
        dst[0] = s[0];
        dst[1] = s[1];
        return;
    }

    const float* bias = z ? bk : bq;
    bf16* Oh = z ? Kh : Qh;
    bf16* Ol = z ? Kl : Ql;
#pragma unroll
    for (int t = 0; t < 4; ++t) {
        float bv = bias[e0 + 16 * t + lr];
#pragma unroll
        for (int r = 0; r < 4; ++r) {
            int m = m0 + w * 16 + lg * 4 + r;
            int b = m >> 10, n = m & (N_ - 1);
            float v = acc[t][r] + bv;
            bf16 hi = (bf16)v;
            size_t idx = ((size_t)(b * H_ + h) * N_ + n) * D_ + 16 * t + lr;
            Oh[idx] = hi;
            Ol[idx] = (bf16)(v - (float)hi);
        }
    }
}

// ---------- fused attention: producer-consumer, TRIPLE-buffered, counted
// vmcnt in producer + raw s_barrier (NOT __syncthreads — that drained the
// producer's in-flight prefetch each phase, collapsing the pipeline to
// depth-1). Producer waves 4-7 stream masks 2 phases ahead; consumer waves
// 0-3 compute (k-split 32 cols). WAR distance = 2 phases; consumer lgkmcnt(0)
// + barrier guards the overwrite. ----------
__global__ __launch_bounds__(512, 4) void attn_kernel(
    const bf16* __restrict__ Qh_, const bf16* __restrict__ Ql_,
    const bf16* __restrict__ Kh_, const bf16* __restrict__ Kl_,
    const bf16* __restrict__ Vt_,
    const float* __restrict__ rn,
    const float* __restrict__ addm, const float* __restrict__ multm,
    float* __restrict__ Opart, float* __restrict__ Mb, float* __restrict__ Lb)
{
    __shared__ alignas(16) float alds[3][16 * 128];   // 24 KB add-mask, 3-deep
    __shared__ alignas(16) float mlds[3][16 * 128];   // 24 KB mult-mask, 3-deep
    __shared__ alignas(16) bf16 plds[4][16 * 40];     // 5 KB -> 53.3 KB total

    // XCD-bijective swizzle: 2048 wg = 8 XCDs x 256; 4 contiguous heads/XCD.
    const int flat = blockIdx.x;
    const int wg = (flat & 7) * 256 + (flat >> 3);
    const int bh = wg >> 6;            // head [0,32)
    const int q0 = (wg & 63) * 16;     // q-block
    const int b = bh >> 3;
    const int tid = threadIdx.x;
    const int w = tid >> 6;            // 0-3 consumer, 4-7 producer
    const int l = tid & 63, lr = l & 15, lg = l >> 4;
    const size_t mb0 = (size_t)bh * N_ * N_;

    const int p = (w >= 4) ? (w - 4) : 0;   // producer id

    f32x4 acc[4] = {};
    float mrun = -3e38f, lrun = 0.f;
    bf16x8 qh0, qh1, ql0, ql1;
    float rnq = 0.f;
    bf16* pw = &plds[w & 3][0];

    // Producer batch: 4 x gload16 (rows 4p..4p+3, 2 rows x 512B per instr)
#define PSTAGE(kv, bi_)                                                        \
    {                                                                          \
        _Pragma("unroll")                                                      \
        for (int j = 0; j < 2; ++j) {                                          \
            const int rp = 4 * p + 2 * j;                                      \
            const int r_ = rp + (l >> 5);                                      \
            const int so = ((l & 31) * 16) ^ ((r_ & 7) << 4);                  \
            gload16((const char*)(addm + mb0 + (size_t)(q0 + r_) * N_ + (kv)) + so, \
                    &alds[bi_][rp * 128]);                                     \
            gload16((const char*)(multm + mb0 + (size_t)(q0 + r_) * N_ + (kv)) + so, \
                    &mlds[bi_][rp * 128]);                                     \
        }                                                                      \
    }

    if (w < 4) {
        const bf16* qb = &Qh_[((size_t)bh * N_ + q0 + lr) * D_];
        const bf16* qlb = &Ql_[((size_t)bh * N_ + q0 + lr) * D_];
        qh0 = *(const bf16x8*)(qb + lg * 8);
        qh1 = *(const bf16x8*)(qb + 32 + lg * 8);
        ql0 = *(const bf16x8*)(qlb + lg * 8);
        ql1 = *(const bf16x8*)(qlb + 32 + lg * 8);
        rnq = rn[b * N_ + q0 + lr] * 0.125f;
    } else {
        // prologue: batch 0 -> buf 0, batch 1 -> buf 1; drain batch 0 only
        PSTAGE(0, 0);
        PSTAGE(128, 1);
        __builtin_amdgcn_sched_barrier(0);
        asm volatile("s_waitcnt vmcnt(4)" ::: "memory");   // batch0 done; batch1 in flight
        __builtin_amdgcn_sched_barrier(0);
    }
    __builtin_amdgcn_s_barrier();   // buf0 ready for phase 0

    for (int t = 0; t < 8; ++t) {
        const int bi = t % 3;

        if (w >= 4) {
            // ---- PRODUCER: issue batch t+2; ensure batch t+1 complete ----
            if (t + 2 < 8) {
                PSTAGE((t + 2) * 128, (t + 2) % 3);
                __builtin_amdgcn_sched_barrier(0);
                asm volatile("s_waitcnt vmcnt(4)" ::: "memory");  // batch t+1 done; t+2 in flight
            } else if (t + 1 < 8) {
                asm volatile("s_waitcnt vmcnt(0)" ::: "memory");  // final batch done
            }
            __builtin_amdgcn_sched_barrier(0);
        } else {
            // ---- CONSUMER: compute phase t from buf bi ----
            const int kw = t * 128 + 32 * w;   // this wave's 32-col slice

            bf16x8 kh[2][2], kl[2][2];
#pragma unroll
            for (int u = 0; u < 2; ++u) {
                const bf16* kp = Kh_ + ((size_t)bh * N_ + kw + 16 * u + lr) * D_ + 8 * lg;
                const bf16* k2 = Kl_ + ((size_t)bh * N_ + kw + 16 * u + lr) * D_ + 8 * lg;
                kh[u][0] = *(const bf16x8*)kp;
                kh[u][1] = *(const bf16x8*)(kp + 32);
                kl[u][0] = *(const bf16x8*)k2;
                kl[u][1] = *(const bf16x8*)(k2 + 32);
            }
            bf16x8 vv[4];
#pragma unroll
            for (int u = 0; u < 4; ++u)
                vv[u] = *(const bf16x8*)(Vt_ + ((size_t)bh * D_ + 16 * u + lr) * N_ + kw + 8 * lg);

            // S^T = K Q^T (hi/lo split)
            f32x4 z[2];
#pragma unroll
            for (int u = 0; u < 2; ++u) {
                f32x4 zz = {};
                zz = MFMA16(kh[u][0], qh0, zz, 0, 0, 0);
                zz = MFMA16(kh[u][1], qh1, zz, 0, 0, 0);
                zz = MFMA16(kh[u][0], ql0, zz, 0, 0, 0);
                zz = MFMA16(kh[u][1], ql1, zz, 0, 0, 0);
                zz = MFMA16(kl[u][0], qh0, zz, 0, 0, 0);
                zz = MFMA16(kl[u][1], qh1, zz, 0, 0, 0);
                z[u] = zz;
            }

            // masks from LDS (swizzled f32x4; row = q = lr)
            f32x4 ma[2], mm[2];
#pragma unroll
            for (int u = 0; u < 2; ++u) {
                const int cdw = 32 * w + 16 * u + 4 * lg;
                const int off = lr * 512 + ((cdw * 4) ^ ((lr & 7) << 4));
                ma[u] = *(const f32x4*)((const char*)&alds[bi][0] + off);
                mm[u] = *(const f32x4*)((const char*)&mlds[bi][0] + off);
            }

            float sv[2][4];
#pragma unroll
            for (int u = 0; u < 2; ++u)
#pragma unroll
                for (int r = 0; r < 4; ++r)
                    sv[u][r] = z[u][r] * rnq + ma[u][r];

            // per-lane online softmax (q = lr; reduce over lg via xor16/32)
            float vmax = sv[0][0];
#pragma unroll
            for (int u = 0; u < 2; ++u)
#pragma unroll
                for (int r = 0; r < 4; ++r) vmax = fmaxf(vmax, sv[u][r]);
            vmax = fmaxf(vmax, __shfl_xor(vmax, 16));
            vmax = fmaxf(vmax, __shfl_xor(vmax, 32));
            float mn = fmaxf(mrun, vmax);
            float rs = __expf(mrun - mn);
            mrun = mn;
            lrun *= rs;
#pragma unroll
            for (int u = 0; u < 4; ++u) acc[u] *= rs;
            float pe[2][4];
            float rsum = 0.f;
#pragma unroll
            for (int u = 0; u < 2; ++u)
#pragma unroll
                for (int r = 0; r < 4; ++r) { pe[u][r] = __expf(sv[u][r] - mn); rsum += pe[u][r]; }
            rsum += __shfl_xor(rsum, 16);
            rsum += __shfl_xor(rsum, 32);
            lrun += rsum;

            // P_eff -> wave-private plds
#pragma unroll
            for (int u = 0; u < 2; ++u) {
                bf16x4 pk;
#pragma unroll
                for (int r = 0; r < 4; ++r) pk[r] = (bf16)(pe[u][r] * mm[u][r]);
                *(bf16x4*)(pw + lr * 40 + 16 * u + 4 * lg) = pk;
            }

            // PV
            bf16x8 pa = *(const bf16x8*)(pw + lr * 40 + 8 * lg);
#pragma unroll
            for (int u = 0; u < 4; ++u)
                acc[u] = MFMA16(vv[u], pa, acc[u], 0, 0, 0);

            // mask ds_reads of this phase complete before barrier (WAR fence)
            __builtin_amdgcn_sched_barrier(0);
            asm volatile("s_waitcnt lgkmcnt(0)" ::: "memory");
            __builtin_amdgcn_sched_barrier(0);
        }

        __builtin_amdgcn_s_barrier();   // phase gate (non-draining)
    }

    // ---- consumer epilogue: per-wave k-chunk partials ----
    if (w < 4) {
        const size_t cb = ((size_t)w * BH_ + bh) * N_;
        float* ob = &Opart[(cb + q0 + lr) * D_];
#pragma unroll
        for (int u = 0; u < 4; ++u)
            *(f32x4*)(ob + 16 * u + 4 * lg) = acc[u];
        if (lg == 0) {
            Mb[cb + q0 + lr] = mrun;
            Lb[cb + q0 + lr] = lrun;
        }
    }
#undef PSTAGE
}

// ---------- merge partials (4 k-chunks) -> normalized attention out ----------
__global__ __launch_bounds__(256) void merge_kernel(
    const float* __restrict__ Opart, const float* __restrict__ Mb,
    const float* __restrict__ Lb,
    bf16* __restrict__ AOh, bf16* __restrict__ AOl, int ks)
{
    int idx = blockIdx.x * 256 + threadIdx.x;
    int bh = idx >> 14;
    int rem = idx & 16383;
    int q = rem >> 4, d4 = rem & 15;

    float M = -3e38f;
    for (int c = 0; c < ks; ++c)
        M = fmaxf(M, Mb[((size_t)c * BH_ + bh) * N_ + q]);
    float L = 0.f;
    f32x4 o = {};
    for (int c = 0; c < ks; ++c) {
        size_t base = ((size_t)c * BH_ + bh) * N_ + q;
        float wgt = __expf(Mb[base] - M);
        L += wgt * Lb[base];
        f32x4 v = *(const f32x4*)&Opart[base * D_ + d4 * 4];
        o += wgt * v;
    }
    float inv = 1.f / L;
    int b = bh >> 3, h = bh & 7;
    size_t ob = ((size_t)b * N_ + q) * E_ + h * D_ + d4 * 4;
    bf16x4 hi, lo;
#pragma unroll
    for (int j = 0; j < 4; ++j) {
        float x = o[j] * inv;
        bf16 hh = (bf16)x;
        hi[j] = hh;
        lo[j] = (bf16)(x - (float)hh);
    }
    *(bf16x4*)&AOh[ob] = hi;
    *(bf16x4*)&AOl[ob] = lo;
}

// ---------- output projection with W-tile LDS staging, fp32 out + bias ----------
__global__ __launch_bounds__(256) void out_gemm(
    const bf16* __restrict__ Ah, const bf16* __restrict__ Al,
    const bf16* __restrict__ Wh, const bf16* __restrict__ Wl,
    const float* __restrict__ bias,
    float* __restrict__ out)
{
    __shared__ alignas(16) bf16 wlds[2][2][64 * 32];
    const int e0 = blockIdx.x * 64;
    const int m0 = blockIdx.y * 64;
    const int tid = threadIdx.x;
    const int w = tid >> 6, l = tid & 63, lr = l & 15, lg = l >> 4;

    const int wrow = 16 * w + (l >> 2);
    const int wcol = 8 * ((l & 3) ^ ((l >> 3) & 3));
    const bf16* whsrc = Wh + (size_t)(e0 + wrow) * E_ + wcol;
    const bf16* wlsrc = Wl + (size_t)(e0 + wrow) * E_ + wcol;

#define WSTAGE(k0, bi) do {                               \
        gload16(whsrc + (k0), &wlds[bi][0][w * 512]);     \
        gload16(wlsrc + (k0), &wlds[bi][1][w * 512]);     \
    } while (0)

    WSTAGE(0, 0);

    f32x4 acc[4] = {};
    const bf16* ah_p = &Ah[(size_t)(m0 + w * 16 + lr) * E_];
    const bf16* al_p = &Al[(size_t)(m0 + w * 16 + lr) * E_];

    for (int it = 0; it < 16; ++it) {
        const int k0 = it * 32;
        const int bi = it & 1;
        if (it < 15) {
            WSTAGE(k0 + 32, bi ^ 1);
            __builtin_amdgcn_sched_barrier(0);
            asm volatile("s_waitcnt vmcnt(2)" ::: "memory");
        } else {
            asm volatile("s_waitcnt vmcnt(0)" ::: "memory");
        }
        __builtin_amdgcn_sched_barrier(0);
        __builtin_amdgcn_s_barrier();

        bf16x8 ah = *(const bf16x8*)(ah_p + k0 + lg * 8);
        bf16x8 al = *(const bf16x8*)(al_p + k0 + lg * 8);
        const char* whb = (const char*)&wlds[bi][0][0];
        const char* wlb = (const char*)&wlds[bi][1][0];
        const int wsw = ((lr >> 1) & 3) << 4;
#pragma unroll
        for (int t = 0; t < 4; ++t) {
            int rb = (16 * t + lr) * 64;
            bf16x8 bh = *(const bf16x8*)(whb + rb + ((lg * 16) ^ wsw));
            bf16x8 bl = *(const bf16x8*)(wlb + rb + ((lg * 16) ^ wsw));
            acc[t] = MFMA16(ah, bh, acc[t], 0, 0, 0);
            acc[t] = MFMA16(al, bh, acc[t], 0, 0, 0);
            acc[t] = MFMA16(ah, bl, acc[t], 0, 0, 0);
        }
        __builtin_amdgcn_s_barrier();
    }
#undef WSTAGE

#pragma unroll
    for (int t = 0; t < 4; ++t) {
        float bv = bias[e0 + 16 * t + lr];
#pragma unroll
        for (int r = 0; r < 4; ++r) {
            int m = m0 + w * 16 + lg * 4 + r;
            out[(size_t)m * E_ + e0 + 16 * t + lr] = acc[t][r] + bv;
        }
    }
}

extern "C" void kernel_launch(void* const* d_in, const int* in_sizes, int n_in,
                              void* d_out, int out_size, void* d_ws, size_t ws_size,
                              hipStream_t stream) {
    const float* X = (const float*)d_in[0];
    const float* rn = (const float*)d_in[1];
    const float* addm = (const float*)d_in[2];
    const float* multm = (const float*)d_in[3];
    const float* Wq = (const float*)d_in[4];
    const float* bq = (const float*)d_in[5];
    const float* Wk = (const float*)d_in[6];
    const float* bk = (const float*)d_in[7];
    const float* Wv = (const float*)d_in[8];
    const float* bv = (const float*)d_in[9];
    const float* Wo = (const float*)d_in[10];
    const float* bo = (const float*)d_in[11];
    float* out = (float*)d_out;

    const size_t SZ_X = (size_t)B_ * N_ * E_;
    const size_t SZ_W = (size_t)E_ * E_;

    bf16* p = (bf16*)d_ws;
    bf16* Xh = p;  p += SZ_X;
    bf16* Xl = p;  p += SZ_X;
    bf16* Wqh = p; p += SZ_W;
    bf16* Wql = p; p += SZ_W;
    bf16* Wkh = p; p += SZ_W;
    bf16* Wkl = p; p += SZ_W;
    bf16* Wvh = p; p += SZ_W;
    bf16* Woh = p; p += SZ_W;
    bf16* Wol = p; p += SZ_W;
    bf16* Qh = p;  p += SZ_X;
    bf16* Ql = p;  p += SZ_X;
    bf16* Kh = p;  p += SZ_X;
    bf16* Kl = p;  p += SZ_X;
    bf16* Vt = p;  p += SZ_X;
    bf16* AOh = p; p += SZ_X;
    bf16* AOl = p; p += SZ_X;

    const int nchunk = 4;   // consumer-wave k-slices
    float* Opart = (float*)p;
    float* Mb = Opart + (size_t)nchunk * BH_ * N_ * D_;
    float* Lb = Mb + (size_t)nchunk * BH_ * N_;

    const int NPREP = B_ * N_ * E_ + 4 * E_ * E_;
    prep_all<<<dim3(NPREP / 256), 256, 0, stream>>>(X, Wq, Wk, Wv, Wo,
        Xh, Xl, Wqh, Wql, Wkh, Wkl, Wvh, Woh, Wol);

    dim3 gq(E_ / 64, (B_ * N_) / 64, 3);
    qkv_gemm<<<gq, 256, 0, stream>>>(Xh, Xl, Wqh, Wql, bq, Wkh, Wkl, bk, Wvh, bv,
                                     Qh, Ql, Kh, Kl, Vt);

    // 32 heads x 64 q-groups = 2048 blocks x 512 threads (4 producer + 4 consumer waves)
    attn_kernel<<<dim3(BH_ * 64), 512, 0, stream>>>(
        Qh, Ql, Kh, Kl, Vt, rn, addm, multm, Opart, Mb, Lb);

    merge_kernel<<<dim3((BH_ * N_ * (D_ / 4)) / 256), 256, 0, stream>>>(
        Opart, Mb, Lb, AOh, AOl, nchunk);

    dim3 gg(E_ / 64, (B_ * N_) / 64);
    out_gemm<<<gg, 256, 0, stream>>>(AOh, AOl, Woh, Wol, bo, out);
}